// Round 4
// baseline (144.356 us; speedup 1.0000x reference)
//
#include <hip/hip_runtime.h>
#include <stdint.h>

#define Bb 8
#define Ll 2048
#define Ss 2048
#define Dd 128
#define NSB 8
#define SCHUNK 256
#define NROWS 16384  // Bb*Ll == Bb*Ss
#define SCALE_LOG2E 92.33248261689366f  // 64 * log2(e); also the fixed softmax max

typedef __attribute__((ext_vector_type(8))) short bf16x8;
typedef __attribute__((ext_vector_type(16))) float f32x16;
typedef __attribute__((ext_vector_type(4))) unsigned u32x4;

__device__ __forceinline__ unsigned f2bf_pack(float a, float b) {
  unsigned ua = __float_as_uint(a); ua += 0x7fffu + ((ua >> 16) & 1u);
  unsigned ub = __float_as_uint(b); ub += 0x7fffu + ((ub >> 16) & 1u);
  return (ua >> 16) | (ub & 0xffff0000u);
}

__device__ __forceinline__ unsigned pkbf(float a, float b) {
#if __has_builtin(__builtin_amdgcn_cvt_pk_bf16_f32)
  auto r = __builtin_amdgcn_cvt_pk_bf16_f32(a, b);  // gfx950 v_cvt_pk_bf16_f32
  return __builtin_bit_cast(unsigned, r);
#else
  return f2bf_pack(a, b);
#endif
}

__device__ __forceinline__ void gl_lds16(const void* g, void* l) {
  __builtin_amdgcn_global_load_lds(
      (const __attribute__((address_space(1))) unsigned*)g,
      (__attribute__((address_space(3))) unsigned*)l, 16, 0, 0);
}

// ---------------- fused pre-pass: Q/K row-normalize -> bf16, V -> V^T bf16 ---
#define TRS 138
extern "C" __global__ __launch_bounds__(256)
void prep_kern(const float* __restrict__ Q, const float* __restrict__ K,
               const float* __restrict__ V,
               unsigned short* __restrict__ Qn, unsigned short* __restrict__ Kn,
               unsigned short* __restrict__ Vt) {
  __shared__ unsigned short T[32 * TRS];
  const int t = threadIdx.x;
  const int bid = blockIdx.x;
  if (bid < 8192) {  // Q/K row normalization, one row per wave
    const int lane = t & 63;
    int row = (bid << 2) + (t >> 6);
    int r = row;
    const float* src = Q; unsigned short* dst = Qn;
    if (row >= NROWS) { r = row - NROWS; src = K; dst = Kn; }
    float2 f = *(const float2*)(src + (size_t)r * Dd + lane * 2);
    float ss = f.x * f.x + f.y * f.y;
#pragma unroll
    for (int m = 1; m < 64; m <<= 1) ss += __shfl_xor(ss, m, 64);
    float inv = 1.0f / fmaxf(sqrtf(ss), 1e-12f);
    *(unsigned*)(dst + (size_t)r * Dd + lane * 2) = pkbf(f.x * inv, f.y * inv);
  } else {  // V transpose: 32-s-row window per block
    const int vb = bid - 8192;
    const int b = vb & 7, sw = vb >> 3;
    const int d4 = t & 31, sr = t >> 5;
#pragma unroll
    for (int p = 0; p < 4; ++p) {
      int sl = p * 8 + sr;
      float4 v = *(const float4*)(V + ((size_t)(b * Ss + sw * 32 + sl)) * Dd + d4 * 4);
      *(unsigned*)&T[sl * TRS + d4 * 4]     = pkbf(v.x, v.y);
      *(unsigned*)&T[sl * TRS + d4 * 4 + 2] = pkbf(v.z, v.w);
    }
    __syncthreads();
    const int so = t & 3, db = t >> 2;
#pragma unroll
    for (int p = 0; p < 2; ++p) {
      int d = p * 64 + db;
      unsigned u[4];
#pragma unroll
      for (int k = 0; k < 4; ++k) {
        unsigned lo = T[(so * 8 + 2 * k) * TRS + d];
        unsigned hi = T[(so * 8 + 2 * k + 1) * TRS + d];
        u[k] = lo | (hi << 16);
      }
      *(uint4*)(Vt + ((size_t)(b * Dd + d)) * Ss + sw * 32 + so * 8) =
          make_uint4(u[0], u[1], u[2], u[3]);
    }
  }
}

// ---------------- main fused attention (S-split flash, FIXED softmax max) ----
// grid 1024: gid = qt*64 + (b*8+sb); WG = 4 waves, each owns 32 q-rows.
// S-chunk 256, tile 32. K via LDS (8 KB dbuf), V direct global->VGPR
// (fragments identical across the 4 waves -> L1-resident). 3 WG/CU.
extern "C" __global__ __launch_bounds__(256, 3)
void attn_kern(const unsigned short* __restrict__ Qn,
               const unsigned short* __restrict__ Kn,
               const unsigned short* __restrict__ Vt,
               unsigned short* __restrict__ Op,
               float* __restrict__ Lp) {
  __shared__ unsigned short Kl[2][8 * 512];  // 8 slots * 1KB, fragment-major
  const int tid = threadIdx.x, wv = tid >> 6, lane = tid & 63;
  const int lm = lane & 31, h = lane >> 5;
  const int gid = blockIdx.x;
  const int grp = gid & 63, qt = gid >> 6;
  const int b = grp >> 3, sb = grp & 7;
  const int sbase = sb * SCHUNK;
  const int qrow = qt * 128 + wv * 32 + lm;

  // Q B-fragments (k = d): held in registers for whole kernel
  const unsigned short* Qrow = Qn + ((size_t)(b * Ll + qrow)) * Dd;
  bf16x8 qf[8];
#pragma unroll
  for (int kt = 0; kt < 8; ++kt)
    qf[kt] = *(const bf16x8*)(Qrow + kt * 16 + h * 8);

  const unsigned short* Kb = Kn + (size_t)b * Ss * Dd;
  const unsigned short* Vb = Vt + (size_t)b * Dd * Ss;

  f32x16 o[4];
#pragma unroll
  for (int i = 0; i < 4; ++i)
#pragma unroll
    for (int r = 0; r < 16; ++r) o[i][r] = 0.f;

  auto stageK = [&](int it, int buf) {
    const int s0 = sbase + it * 32;
#pragma unroll
    for (int i = 0; i < 2; ++i) {
      const int kt = wv * 2 + i;  // slot = kt
      gl_lds16(Kb + (size_t)(s0 + lm) * Dd + kt * 16 + h * 8, &Kl[buf][kt * 512]);
    }
  };
  stageK(0, 0);

  float lrun = 0.f;

#pragma unroll 1
  for (int it = 0; it < 8; ++it) {
    __syncthreads();  // drains vmcnt: cur K staged, prev buffer reads done
    const int cur = it & 1;
    const int s0 = sbase + it * 32;
    // V fragments: direct global loads (identical across waves; L1 hits)
    uint4 vfr[8];
#pragma unroll
    for (int dblk = 0; dblk < 4; ++dblk)
#pragma unroll
      for (int t = 0; t < 2; ++t)
        vfr[dblk * 2 + t] =
            *(const uint4*)(Vb + (size_t)(dblk * 32 + lm) * Ss + s0 + t * 16 + h * 8);
    if (it + 1 < 8) stageK(it + 1, cur ^ 1);

    // S^T = K · Q^T  (M=s 32, N=m 32, K=d 8x16)
    f32x16 acc;
#pragma unroll
    for (int r = 0; r < 16; ++r) acc[r] = 0.f;
#pragma unroll
    for (int kt = 0; kt < 8; ++kt) {
      bf16x8 kf = *(const bf16x8*)&Kl[cur][kt * 512 + lane * 8];
      acc = __builtin_amdgcn_mfma_f32_32x32x16_bf16(kf, qf[kt], acc, 0, 0, 0);
    }

    // fixed-max softmax: p = 2^(st*SC - SC), elementwise independent
    float ls = 0.f;
#pragma unroll
    for (int t = 0; t < 2; ++t) {  // 16-s block; P B-frag built via xor-32 shuffles
      float p[8];
#pragma unroll
      for (int j = 0; j < 8; ++j)
        p[j] = __builtin_amdgcn_exp2f(
            __builtin_fmaf(acc[t * 8 + j], SCALE_LOG2E, -SCALE_LOG2E));
      ls += ((p[0] + p[1]) + (p[2] + p[3])) + ((p[4] + p[5]) + (p[6] + p[7]));
      unsigned u0 = pkbf(p[0], p[1]), u1 = pkbf(p[2], p[3]);
      unsigned u2 = pkbf(p[4], p[5]), u3 = pkbf(p[6], p[7]);
      unsigned s0p = (unsigned)__shfl_xor((int)u0, 32, 64);
      unsigned s1p = (unsigned)__shfl_xor((int)u1, 32, 64);
      unsigned s2p = (unsigned)__shfl_xor((int)u2, 32, 64);
      unsigned s3p = (unsigned)__shfl_xor((int)u3, 32, 64);
      u32x4 fr;
      fr.x = h ? s2p : u0;  // j0j1
      fr.y = h ? s3p : u1;  // j2j3
      fr.z = h ? u2 : s0p;  // j4j5
      fr.w = h ? u3 : s1p;  // j6j7
      bf16x8 pf = __builtin_bit_cast(bf16x8, fr);
      // O^T += V^T · P^T  (M=d 4x32, N=m 32, K=s 16)
#pragma unroll
      for (int dblk = 0; dblk < 4; ++dblk) {
        bf16x8 vf = __builtin_bit_cast(bf16x8, vfr[dblk * 2 + t]);
        o[dblk] = __builtin_amdgcn_mfma_f32_32x32x16_bf16(vf, pf, o[dblk], 0, 0, 0);
      }
    }
    lrun += ls;
  }

  // epilogue: partial (unnormalized) O in bf16 + per-row l (shared fixed max)
  const float lt = lrun + __shfl_xor(lrun, 32, 64);
  unsigned short* Ob = Op + ((size_t)sb * NROWS + b * Ll + qrow) * Dd;
#pragma unroll
  for (int dblk = 0; dblk < 4; ++dblk)
#pragma unroll
    for (int g = 0; g < 4; ++g) {
      uint2 w;
      w.x = pkbf(o[dblk][g * 4 + 0], o[dblk][g * 4 + 1]);
      w.y = pkbf(o[dblk][g * 4 + 2], o[dblk][g * 4 + 3]);
      *(uint2*)(Ob + dblk * 32 + g * 8 + h * 4) = w;  // d = 32*dblk + 8*g + 4*h
    }
  if (h == 0) Lp[sb * NROWS + b * Ll + qrow] = lt;
}

// ---------------- combine the NSB S-chunk partials (pure sum: shared max) ----
extern "C" __global__ __launch_bounds__(256)
void comb_kern(const unsigned short* __restrict__ Op,
               const float* __restrict__ Lp, float* __restrict__ Out) {
  const int idx = blockIdx.x * 256 + threadIdx.x;  // one thread per 4 d
  const int row = idx >> 5;
  const int dof = (idx & 31) * 4;
  float den = 0.f;
#pragma unroll
  for (int s = 0; s < NSB; ++s) den += Lp[s * NROWS + row];
  float a0 = 0.f, a1 = 0.f, a2 = 0.f, a3 = 0.f;
#pragma unroll
  for (int s = 0; s < NSB; ++s) {
    uint2 v = *(const uint2*)(Op + ((size_t)s * NROWS + row) * Dd + dof);
    a0 += __uint_as_float(v.x << 16);
    a1 += __uint_as_float(v.x & 0xffff0000u);
    a2 += __uint_as_float(v.y << 16);
    a3 += __uint_as_float(v.y & 0xffff0000u);
  }
  const float inv = 1.f / den;
  float4 r; r.x = a0 * inv; r.y = a1 * inv; r.z = a2 * inv; r.w = a3 * inv;
  *(float4*)(Out + (size_t)row * Dd + dof) = r;
}

extern "C" void kernel_launch(void* const* d_in, const int* in_sizes, int n_in,
                              void* d_out, int out_size, void* d_ws, size_t ws_size,
                              hipStream_t stream) {
  const float* Q = (const float*)d_in[0];
  const float* K = (const float*)d_in[1];
  const float* V = (const float*)d_in[2];
  float* Out = (float*)d_out;
  unsigned short* Qn = (unsigned short*)d_ws;                  // 4 MiB
  unsigned short* Kn = Qn + (size_t)NROWS * Dd;                // 4 MiB
  unsigned short* Vt = Kn + (size_t)NROWS * Dd;                // 4 MiB
  unsigned short* Op = Vt + (size_t)Bb * Dd * Ss;              // 32 MiB (bf16 partials)
  float* Lp = (float*)(Op + (size_t)NSB * NROWS * Dd);         // 512 KiB
  hipLaunchKernelGGL(prep_kern, dim3(8192 + 512), dim3(256), 0, stream, Q, K, V, Qn, Kn, Vt);
  hipLaunchKernelGGL(attn_kern, dim3(1024), dim3(256), 0, stream, Qn, Kn, Vt, Op, Lp);
  hipLaunchKernelGGL(comb_kern, dim3(2048), dim3(256), 0, stream, Op, Lp, Out);
}

// Round 5
// 122.104 us; speedup vs baseline: 1.1822x; 1.1822x over previous
//
#include <hip/hip_runtime.h>
#include <stdint.h>

#define Bb 8
#define Ll 2048
#define Ss 2048
#define Dd 128
#define NSB 8
#define SCHUNK 256
#define NROWS 16384  // Bb*Ll == Bb*Ss
#define SCALE_LOG2E 92.33248261689366f  // 64 * log2(e); also the fixed softmax max

typedef __attribute__((ext_vector_type(8))) short bf16x8;
typedef __attribute__((ext_vector_type(16))) float f32x16;
typedef __attribute__((ext_vector_type(4))) unsigned u32x4;

__device__ __forceinline__ unsigned f2bf_pack(float a, float b) {
  unsigned ua = __float_as_uint(a); ua += 0x7fffu + ((ua >> 16) & 1u);
  unsigned ub = __float_as_uint(b); ub += 0x7fffu + ((ub >> 16) & 1u);
  return (ua >> 16) | (ub & 0xffff0000u);
}

__device__ __forceinline__ unsigned pkbf(float a, float b) {
#if __has_builtin(__builtin_amdgcn_cvt_pk_bf16_f32)
  auto r = __builtin_amdgcn_cvt_pk_bf16_f32(a, b);  // gfx950 v_cvt_pk_bf16_f32
  return __builtin_bit_cast(unsigned, r);
#else
  return f2bf_pack(a, b);
#endif
}

__device__ __forceinline__ void gl_lds16(const void* g, void* l) {
  __builtin_amdgcn_global_load_lds(
      (const __attribute__((address_space(1))) unsigned*)g,
      (__attribute__((address_space(3))) unsigned*)l, 16, 0, 0);
}

// Fragment-major layouts (per 32-s block = 8 slots of 1 KB = 8 KB):
//   Kf[b][sblk][kt][lane][j] : lane l of slot kt holds K[s=sblk*32+(l&31)][d=kt*16+(l>>5)*8+j]
//   Vf[b][sblk][dblk*2+t2][lane][j] : lane l holds V^T[d=dblk*32+(l&31)][s=sblk*32+t2*16+(l>>5)*8+j]

// ---------------- fused pre-pass: Q/K normalize -> bf16 (K in frag order),
// ----------------                 V -> V^T bf16 in frag order ---------------
#define TRS 138
extern "C" __global__ __launch_bounds__(256)
void prep_kern(const float* __restrict__ Q, const float* __restrict__ K,
               const float* __restrict__ V,
               unsigned short* __restrict__ Qn, unsigned short* __restrict__ Kf,
               unsigned short* __restrict__ Vf) {
  __shared__ unsigned short T[32 * TRS];
  const int t = threadIdx.x;
  const int bid = blockIdx.x;
  if (bid < 8192) {  // Q/K row normalization, one row per wave
    const int lane = t & 63;
    int row = (bid << 2) + (t >> 6);
    const bool isK = row >= NROWS;
    const int r = isK ? row - NROWS : row;
    const float* src = isK ? K : Q;
    float2 f = *(const float2*)(src + (size_t)r * Dd + lane * 2);
    float ss = f.x * f.x + f.y * f.y;
#pragma unroll
    for (int m = 1; m < 64; m <<= 1) ss += __shfl_xor(ss, m, 64);
    float inv = 1.0f / fmaxf(sqrtf(ss), 1e-12f);
    unsigned w = pkbf(f.x * inv, f.y * inv);
    if (!isK) {
      *(unsigned*)(Qn + (size_t)r * Dd + lane * 2) = w;  // row-major Q
    } else {
      // fragment-major K: d = 2*lane -> kt=lane>>3, h=(lane>>2)&1, j=(2*lane)&7
      const int srow = r & (Ss - 1);          // s within batch (r = b*Ss + s)
      const int b = r >> 11;
      size_t off = (((size_t)b * 64 + (srow >> 5)) * 8 + (lane >> 3)) * 512 +
                   (((lane >> 2) & 1) * 32 + (srow & 31)) * 8 + ((2 * lane) & 7);
      *(unsigned*)(Kf + off) = w;
    }
  } else {  // V transpose: 32-s window per block -> fragment-major Vf
    const int vb = bid - 8192;
    const int b = vb & 7, sw = vb >> 3;  // sw = sblk (0..63)
    const int d4 = t & 31, sr = t >> 5;
#pragma unroll
    for (int p = 0; p < 4; ++p) {
      int sl = p * 8 + sr;
      float4 v = *(const float4*)(V + ((size_t)(b * Ss + sw * 32 + sl)) * Dd + d4 * 4);
      *(unsigned*)&T[sl * TRS + d4 * 4]     = pkbf(v.x, v.y);
      *(unsigned*)&T[sl * TRS + d4 * 4 + 2] = pkbf(v.z, v.w);
    }
    __syncthreads();
    const int so = t & 3, db = t >> 2;   // so -> (t2,h), db -> d (0..63 per p)
    const int t2 = so >> 1, h = so & 1;
#pragma unroll
    for (int p = 0; p < 2; ++p) {
      int d = p * 64 + db;
      unsigned u[4];
#pragma unroll
      for (int k = 0; k < 4; ++k) {
        unsigned lo = T[(so * 8 + 2 * k) * TRS + d];
        unsigned hi = T[(so * 8 + 2 * k + 1) * TRS + d];
        u[k] = lo | (hi << 16);
      }
      const int vslot = (d >> 5) * 2 + t2;
      size_t off = (((size_t)b * 64 + sw) * 8 + vslot) * 512 +
                   (h * 32 + (d & 31)) * 8;
      *(uint4*)(Vf + off) = make_uint4(u[0], u[1], u[2], u[3]);
    }
  }
}

// ---------------- main fused attention (S-split flash, fixed softmax max) ---
// grid 1024: gid = qt*64 + b*8 + sb; WG = 4 waves, each owns 32 q-rows.
// S-chunk 256, tile 32. K,V staged via perfectly-coalesced gl_lds16 from
// fragment-major Kf/Vf. LDS 32 KB dbuf -> 4 WG/CU (16 waves).
extern "C" __global__ __launch_bounds__(256, 4)
void attn_kern(const unsigned short* __restrict__ Qn,
               const unsigned short* __restrict__ Kf,
               const unsigned short* __restrict__ Vf,
               unsigned short* __restrict__ Op,
               float* __restrict__ Lp) {
  __shared__ unsigned short Kl[2][8 * 512];  // 8 slots * 1KB
  __shared__ unsigned short Vl[2][8 * 512];
  const int tid = threadIdx.x, wv = tid >> 6, lane = tid & 63;
  const int lm = lane & 31, h = lane >> 5;
  const int gid = blockIdx.x;
  const int qt = gid >> 6, b = (gid >> 3) & 7, sb = gid & 7;
  const int sblk0 = sb * (SCHUNK / 32);
  const int qrow = qt * 128 + wv * 32 + lm;

  // Q B-fragments (k = d): registers for whole kernel
  const unsigned short* Qrow = Qn + ((size_t)(b * Ll + qrow)) * Dd;
  bf16x8 qf[8];
#pragma unroll
  for (int kt = 0; kt < 8; ++kt)
    qf[kt] = *(const bf16x8*)(Qrow + kt * 16 + h * 8);

  const unsigned short* Kc = Kf + ((size_t)b * 64 + sblk0) * 8 * 512;
  const unsigned short* Vc = Vf + ((size_t)b * 64 + sblk0) * 8 * 512;

  f32x16 o[4];
#pragma unroll
  for (int i = 0; i < 4; ++i)
#pragma unroll
    for (int r = 0; r < 16; ++r) o[i][r] = 0.f;

  auto stage = [&](int it, int buf) {
    const size_t base = (size_t)it * 4096;  // 8 slots * 512 ushorts
#pragma unroll
    for (int i = 0; i < 2; ++i) {
      const int sl = wv * 2 + i;
      gl_lds16(Kc + base + sl * 512 + lane * 8, &Kl[buf][sl * 512]);
      gl_lds16(Vc + base + sl * 512 + lane * 8, &Vl[buf][sl * 512]);
    }
  };
  stage(0, 0);

  float lrun = 0.f;

#pragma unroll 1
  for (int it = 0; it < 8; ++it) {
    __syncthreads();  // drains vmcnt: cur staged, prev buffer reads done
    const int cur = it & 1;
    if (it + 1 < 8) stage(it + 1, cur ^ 1);

    // S^T = K · Q^T  (M=s 32, N=m 32, K=d 8x16)
    f32x16 acc;
#pragma unroll
    for (int r = 0; r < 16; ++r) acc[r] = 0.f;
#pragma unroll
    for (int kt = 0; kt < 8; ++kt) {
      bf16x8 kf = *(const bf16x8*)&Kl[cur][kt * 512 + lane * 8];
      acc = __builtin_amdgcn_mfma_f32_32x32x16_bf16(kf, qf[kt], acc, 0, 0, 0);
    }

    // fixed-max softmax: p = 2^(st*SC - SC), elementwise independent
    float ls = 0.f;
#pragma unroll
    for (int t = 0; t < 2; ++t) {  // 16-s block; P B-frag via xor-32 shuffles
      float p[8];
#pragma unroll
      for (int j = 0; j < 8; ++j)
        p[j] = __builtin_amdgcn_exp2f(
            __builtin_fmaf(acc[t * 8 + j], SCALE_LOG2E, -SCALE_LOG2E));
      ls += ((p[0] + p[1]) + (p[2] + p[3])) + ((p[4] + p[5]) + (p[6] + p[7]));
      unsigned u0 = pkbf(p[0], p[1]), u1 = pkbf(p[2], p[3]);
      unsigned u2 = pkbf(p[4], p[5]), u3 = pkbf(p[6], p[7]);
      unsigned s0p = (unsigned)__shfl_xor((int)u0, 32, 64);
      unsigned s1p = (unsigned)__shfl_xor((int)u1, 32, 64);
      unsigned s2p = (unsigned)__shfl_xor((int)u2, 32, 64);
      unsigned s3p = (unsigned)__shfl_xor((int)u3, 32, 64);
      u32x4 fr;
      fr.x = h ? s2p : u0;  // j0j1
      fr.y = h ? s3p : u1;  // j2j3
      fr.z = h ? u2 : s0p;  // j4j5
      fr.w = h ? u3 : s1p;  // j6j7
      bf16x8 pf = __builtin_bit_cast(bf16x8, fr);
      // O^T += V^T · P^T  (M=d 4x32, N=m 32, K=s 16)
#pragma unroll
      for (int dblk = 0; dblk < 4; ++dblk) {
        bf16x8 vf = *(const bf16x8*)&Vl[cur][(dblk * 2 + t) * 512 + lane * 8];
        o[dblk] = __builtin_amdgcn_mfma_f32_32x32x16_bf16(vf, pf, o[dblk], 0, 0, 0);
      }
    }
    lrun += ls;
  }

  // epilogue: partial (unnormalized) O in bf16 + per-row l (shared fixed max)
  const float lt = lrun + __shfl_xor(lrun, 32, 64);
  unsigned short* Ob = Op + ((size_t)sb * NROWS + b * Ll + qrow) * Dd;
#pragma unroll
  for (int dblk = 0; dblk < 4; ++dblk)
#pragma unroll
    for (int g = 0; g < 4; ++g) {
      uint2 w;
      w.x = pkbf(o[dblk][g * 4 + 0], o[dblk][g * 4 + 1]);
      w.y = pkbf(o[dblk][g * 4 + 2], o[dblk][g * 4 + 3]);
      *(uint2*)(Ob + dblk * 32 + g * 8 + h * 4) = w;  // d = 32*dblk + 8*g + 4*h
    }
  if (h == 0) Lp[sb * NROWS + b * Ll + qrow] = lt;
}

// ---------------- combine the NSB S-chunk partials (pure sum: shared max) ---
extern "C" __global__ __launch_bounds__(256)
void comb_kern(const unsigned short* __restrict__ Op,
               const float* __restrict__ Lp, float* __restrict__ Out) {
  const int idx = blockIdx.x * 256 + threadIdx.x;  // one thread per 4 d
  const int row = idx >> 5;
  const int dof = (idx & 31) * 4;
  float den = 0.f;
#pragma unroll
  for (int s = 0; s < NSB; ++s) den += Lp[s * NROWS + row];
  float a0 = 0.f, a1 = 0.f, a2 = 0.f, a3 = 0.f;
#pragma unroll
  for (int s = 0; s < NSB; ++s) {
    uint2 v = *(const uint2*)(Op + ((size_t)s * NROWS + row) * Dd + dof);
    a0 += __uint_as_float(v.x << 16);
    a1 += __uint_as_float(v.x & 0xffff0000u);
    a2 += __uint_as_float(v.y << 16);
    a3 += __uint_as_float(v.y & 0xffff0000u);
  }
  const float inv = 1.f / den;
  float4 r; r.x = a0 * inv; r.y = a1 * inv; r.z = a2 * inv; r.w = a3 * inv;
  *(float4*)(Out + (size_t)row * Dd + dof) = r;
}

extern "C" void kernel_launch(void* const* d_in, const int* in_sizes, int n_in,
                              void* d_out, int out_size, void* d_ws, size_t ws_size,
                              hipStream_t stream) {
  const float* Q = (const float*)d_in[0];
  const float* K = (const float*)d_in[1];
  const float* V = (const float*)d_in[2];
  float* Out = (float*)d_out;
  unsigned short* Qn = (unsigned short*)d_ws;                  // 4 MiB
  unsigned short* Kf = Qn + (size_t)NROWS * Dd;                // 4 MiB (frag-major)
  unsigned short* Vf = Kf + (size_t)NROWS * Dd;                // 4 MiB (frag-major)
  unsigned short* Op = Vf + (size_t)Bb * Dd * Ss;              // 32 MiB (bf16 partials)
  float* Lp = (float*)(Op + (size_t)NSB * NROWS * Dd);         // 512 KiB
  hipLaunchKernelGGL(prep_kern, dim3(8192 + 512), dim3(256), 0, stream, Q, K, V, Qn, Kf, Vf);
  hipLaunchKernelGGL(attn_kern, dim3(1024), dim3(256), 0, stream, Qn, Kf, Vf, Op, Lp);
  hipLaunchKernelGGL(comb_kern, dim3(2048), dim3(256), 0, stream, Op, Lp, Out);
}

// Round 6
// 122.023 us; speedup vs baseline: 1.1830x; 1.0007x over previous
//
#include <hip/hip_runtime.h>
#include <stdint.h>

#define Bb 8
#define Ll 2048
#define Ss 2048
#define Dd 128
#define NSB 8
#define SCHUNK 256
#define NROWS 16384  // Bb*Ll == Bb*Ss
#define SCALE_LOG2E 92.33248261689366f  // 64 * log2(e); also the fixed softmax max

typedef __attribute__((ext_vector_type(8))) short bf16x8;
typedef __attribute__((ext_vector_type(16))) float f32x16;
typedef __attribute__((ext_vector_type(4))) unsigned u32x4;

__device__ __forceinline__ unsigned f2bf_pack(float a, float b) {
  unsigned ua = __float_as_uint(a); ua += 0x7fffu + ((ua >> 16) & 1u);
  unsigned ub = __float_as_uint(b); ub += 0x7fffu + ((ub >> 16) & 1u);
  return (ua >> 16) | (ub & 0xffff0000u);
}

__device__ __forceinline__ unsigned pkbf(float a, float b) {
#if __has_builtin(__builtin_amdgcn_cvt_pk_bf16_f32)
  auto r = __builtin_amdgcn_cvt_pk_bf16_f32(a, b);  // gfx950 v_cvt_pk_bf16_f32
  return __builtin_bit_cast(unsigned, r);
#else
  return f2bf_pack(a, b);
#endif
}

// Fragment-major layouts (per 32-s block = 8 slots of 1 KB = 8 KB):
//   Kf[b][sblk][kt][lane][j] : lane l of slot kt holds K[s=sblk*32+(l&31)][d=kt*16+(l>>5)*8+j]
//   Vf[b][sblk][dblk*2+t2][lane][j] : lane l holds V^T[d=dblk*32+(l&31)][s=sblk*32+t2*16+(l>>5)*8+j]

// ---------------- fused pre-pass: Q/K normalize -> bf16 (K in frag order),
// ----------------                 V -> V^T bf16 in frag order ---------------
#define TRS 138
extern "C" __global__ __launch_bounds__(256)
void prep_kern(const float* __restrict__ Q, const float* __restrict__ K,
               const float* __restrict__ V,
               unsigned short* __restrict__ Qn, unsigned short* __restrict__ Kf,
               unsigned short* __restrict__ Vf) {
  __shared__ unsigned short T[32 * TRS];
  const int t = threadIdx.x;
  const int bid = blockIdx.x;
  if (bid < 8192) {  // Q/K row normalization, one row per wave
    const int lane = t & 63;
    int row = (bid << 2) + (t >> 6);
    const bool isK = row >= NROWS;
    const int r = isK ? row - NROWS : row;
    const float* src = isK ? K : Q;
    float2 f = *(const float2*)(src + (size_t)r * Dd + lane * 2);
    float ss = f.x * f.x + f.y * f.y;
#pragma unroll
    for (int m = 1; m < 64; m <<= 1) ss += __shfl_xor(ss, m, 64);
    float inv = 1.0f / fmaxf(sqrtf(ss), 1e-12f);
    unsigned w = pkbf(f.x * inv, f.y * inv);
    if (!isK) {
      *(unsigned*)(Qn + (size_t)r * Dd + lane * 2) = w;  // row-major Q
    } else {
      // fragment-major K: d = 2*lane -> kt=lane>>3, h=(lane>>2)&1, j=(2*lane)&7
      const int srow = r & (Ss - 1);          // s within batch (r = b*Ss + s)
      const int b = r >> 11;
      size_t off = (((size_t)b * 64 + (srow >> 5)) * 8 + (lane >> 3)) * 512 +
                   (((lane >> 2) & 1) * 32 + (srow & 31)) * 8 + ((2 * lane) & 7);
      *(unsigned*)(Kf + off) = w;
    }
  } else {  // V transpose: 32-s window per block -> fragment-major Vf
    const int vb = bid - 8192;
    const int b = vb & 7, sw = vb >> 3;  // sw = sblk (0..63)
    const int d4 = t & 31, sr = t >> 5;
#pragma unroll
    for (int p = 0; p < 4; ++p) {
      int sl = p * 8 + sr;
      float4 v = *(const float4*)(V + ((size_t)(b * Ss + sw * 32 + sl)) * Dd + d4 * 4);
      *(unsigned*)&T[sl * TRS + d4 * 4]     = pkbf(v.x, v.y);
      *(unsigned*)&T[sl * TRS + d4 * 4 + 2] = pkbf(v.z, v.w);
    }
    __syncthreads();
    const int so = t & 3, db = t >> 2;   // so -> (t2,h), db -> d (0..63 per p)
    const int t2 = so >> 1, h = so & 1;
#pragma unroll
    for (int p = 0; p < 2; ++p) {
      int d = p * 64 + db;
      unsigned u[4];
#pragma unroll
      for (int k = 0; k < 4; ++k) {
        unsigned lo = T[(so * 8 + 2 * k) * TRS + d];
        unsigned hi = T[(so * 8 + 2 * k + 1) * TRS + d];
        u[k] = lo | (hi << 16);
      }
      const int vslot = (d >> 5) * 2 + t2;
      size_t off = (((size_t)b * 64 + sw) * 8 + vslot) * 512 +
                   (h * 32 + (d & 31)) * 8;
      *(uint4*)(Vf + off) = make_uint4(u[0], u[1], u[2], u[3]);
    }
  }
}

// ---------------- main fused attention: barrier-free, LDS-free -------------
// grid 1024: gid = qt*64 + b*8 + sb; WG = 4 independent waves, 32 q-rows each.
// K,V fragments loaded straight global->VGPR from fragment-major Kf/Vf
// (lane-contiguous 16 B => perfectly coalesced; per-XCD chunk 1 MB L2-resident,
// co-resident WGs on a CU share identical tiles => L1 hits). No __syncthreads.
extern "C" __global__ __launch_bounds__(256, 3)
void attn_kern(const unsigned short* __restrict__ Qn,
               const unsigned short* __restrict__ Kf,
               const unsigned short* __restrict__ Vf,
               unsigned short* __restrict__ Op,
               float* __restrict__ Lp) {
  const int tid = threadIdx.x, wv = tid >> 6, lane = tid & 63;
  const int lm = lane & 31, h = lane >> 5;
  const int gid = blockIdx.x;
  const int qt = gid >> 6, b = (gid >> 3) & 7, sb = gid & 7;
  const int sblk0 = sb * (SCHUNK / 32);
  const int qrow = qt * 128 + wv * 32 + lm;

  // Q B-fragments (k = d): registers for whole kernel
  const unsigned short* Qrow = Qn + ((size_t)(b * Ll + qrow)) * Dd;
  bf16x8 qf[8];
#pragma unroll
  for (int kt = 0; kt < 8; ++kt)
    qf[kt] = *(const bf16x8*)(Qrow + kt * 16 + h * 8);

  const unsigned short* Kc = Kf + ((size_t)b * 64 + sblk0) * 8 * 512 + lane * 8;
  const unsigned short* Vc = Vf + ((size_t)b * 64 + sblk0) * 8 * 512 + lane * 8;

  f32x16 o[4];
#pragma unroll
  for (int i = 0; i < 4; ++i)
#pragma unroll
    for (int r = 0; r < 16; ++r) o[i][r] = 0.f;

  float lrun = 0.f;

#pragma unroll 1
  for (int it = 0; it < 8; ++it) {
    const size_t base = (size_t)it * 4096;  // 8 slots * 512 ushorts

    // K fragments for this 32-s tile (8 x dwordx4, lane-contiguous)
    bf16x8 kfr[8];
#pragma unroll
    for (int kt = 0; kt < 8; ++kt)
      kfr[kt] = *(const bf16x8*)(Kc + base + kt * 512);

    // S^T = K · Q^T  (M=s 32, N=m 32, K=d 8x16)
    f32x16 acc;
#pragma unroll
    for (int r = 0; r < 16; ++r) acc[r] = 0.f;
#pragma unroll
    for (int kt = 0; kt < 8; ++kt)
      acc = __builtin_amdgcn_mfma_f32_32x32x16_bf16(kfr[kt], qf[kt], acc, 0, 0, 0);

    // V fragments (latency covered by exp/pack phase below)
    bf16x8 vfr[8];
#pragma unroll
    for (int vs = 0; vs < 8; ++vs)
      vfr[vs] = *(const bf16x8*)(Vc + base + vs * 512);

    // fixed-max softmax: p = 2^(st*SC - SC), elementwise independent
    float ls = 0.f;
#pragma unroll
    for (int t = 0; t < 2; ++t) {  // 16-s block; P B-frag via xor-32 shuffles
      float p[8];
#pragma unroll
      for (int j = 0; j < 8; ++j)
        p[j] = __builtin_amdgcn_exp2f(
            __builtin_fmaf(acc[t * 8 + j], SCALE_LOG2E, -SCALE_LOG2E));
      ls += ((p[0] + p[1]) + (p[2] + p[3])) + ((p[4] + p[5]) + (p[6] + p[7]));
      unsigned u0 = pkbf(p[0], p[1]), u1 = pkbf(p[2], p[3]);
      unsigned u2 = pkbf(p[4], p[5]), u3 = pkbf(p[6], p[7]);
      unsigned s0p = (unsigned)__shfl_xor((int)u0, 32, 64);
      unsigned s1p = (unsigned)__shfl_xor((int)u1, 32, 64);
      unsigned s2p = (unsigned)__shfl_xor((int)u2, 32, 64);
      unsigned s3p = (unsigned)__shfl_xor((int)u3, 32, 64);
      u32x4 fr;
      fr.x = h ? s2p : u0;  // j0j1
      fr.y = h ? s3p : u1;  // j2j3
      fr.z = h ? u2 : s0p;  // j4j5
      fr.w = h ? u3 : s1p;  // j6j7
      bf16x8 pf = __builtin_bit_cast(bf16x8, fr);
      // O^T += V^T · P^T  (M=d 4x32, N=m 32, K=s 16)
#pragma unroll
      for (int dblk = 0; dblk < 4; ++dblk)
        o[dblk] = __builtin_amdgcn_mfma_f32_32x32x16_bf16(vfr[dblk * 2 + t], pf,
                                                          o[dblk], 0, 0, 0);
    }
    lrun += ls;
  }

  // epilogue: partial (unnormalized) O in bf16 + per-row l (shared fixed max)
  const float lt = lrun + __shfl_xor(lrun, 32, 64);
  unsigned short* Ob = Op + ((size_t)sb * NROWS + b * Ll + qrow) * Dd;
#pragma unroll
  for (int dblk = 0; dblk < 4; ++dblk)
#pragma unroll
    for (int g = 0; g < 4; ++g) {
      uint2 w;
      w.x = pkbf(o[dblk][g * 4 + 0], o[dblk][g * 4 + 1]);
      w.y = pkbf(o[dblk][g * 4 + 2], o[dblk][g * 4 + 3]);
      *(uint2*)(Ob + dblk * 32 + g * 8 + h * 4) = w;  // d = 32*dblk + 8*g + 4*h
    }
  if (h == 0) Lp[sb * NROWS + b * Ll + qrow] = lt;
}

// ---------------- combine the NSB S-chunk partials (pure sum: shared max) ---
extern "C" __global__ __launch_bounds__(256)
void comb_kern(const unsigned short* __restrict__ Op,
               const float* __restrict__ Lp, float* __restrict__ Out) {
  const int idx = blockIdx.x * 256 + threadIdx.x;  // one thread per 4 d
  const int row = idx >> 5;
  const int dof = (idx & 31) * 4;
  float den = 0.f;
#pragma unroll
  for (int s = 0; s < NSB; ++s) den += Lp[s * NROWS + row];
  float a0 = 0.f, a1 = 0.f, a2 = 0.f, a3 = 0.f;
#pragma unroll
  for (int s = 0; s < NSB; ++s) {
    uint2 v = *(const uint2*)(Op + ((size_t)s * NROWS + row) * Dd + dof);
    a0 += __uint_as_float(v.x << 16);
    a1 += __uint_as_float(v.x & 0xffff0000u);
    a2 += __uint_as_float(v.y << 16);
    a3 += __uint_as_float(v.y & 0xffff0000u);
  }
  const float inv = 1.f / den;
  float4 r; r.x = a0 * inv; r.y = a1 * inv; r.z = a2 * inv; r.w = a3 * inv;
  *(float4*)(Out + (size_t)row * Dd + dof) = r;
}

extern "C" void kernel_launch(void* const* d_in, const int* in_sizes, int n_in,
                              void* d_out, int out_size, void* d_ws, size_t ws_size,
                              hipStream_t stream) {
  const float* Q = (const float*)d_in[0];
  const float* K = (const float*)d_in[1];
  const float* V = (const float*)d_in[2];
  float* Out = (float*)d_out;
  unsigned short* Qn = (unsigned short*)d_ws;                  // 4 MiB
  unsigned short* Kf = Qn + (size_t)NROWS * Dd;                // 4 MiB (frag-major)
  unsigned short* Vf = Kf + (size_t)NROWS * Dd;                // 4 MiB (frag-major)
  unsigned short* Op = Vf + (size_t)Bb * Dd * Ss;              // 32 MiB (bf16 partials)
  float* Lp = (float*)(Op + (size_t)NSB * NROWS * Dd);         // 512 KiB
  hipLaunchKernelGGL(prep_kern, dim3(8192 + 512), dim3(256), 0, stream, Q, K, V, Qn, Kf, Vf);
  hipLaunchKernelGGL(attn_kern, dim3(1024), dim3(256), 0, stream, Qn, Kf, Vf, Op, Lp);
  hipLaunchKernelGGL(comb_kern, dim3(2048), dim3(256), 0, stream, Op, Lp, Out);
}

// Round 7
// 107.156 us; speedup vs baseline: 1.3472x; 1.1387x over previous
//
#include <hip/hip_runtime.h>
#include <stdint.h>

#define Bb 8
#define Ll 2048
#define Ss 2048
#define Dd 128
#define NSB 4
#define SCHUNK 512
#define NROWS 16384  // Bb*Ll == Bb*Ss
#define SCALE_LOG2E 92.33248261689366f  // 64 * log2(e); also the fixed softmax max

typedef __attribute__((ext_vector_type(8))) short bf16x8;
typedef __attribute__((ext_vector_type(16))) float f32x16;

__device__ __forceinline__ unsigned f2bf_pack(float a, float b) {
  unsigned ua = __float_as_uint(a); ua += 0x7fffu + ((ua >> 16) & 1u);
  unsigned ub = __float_as_uint(b); ub += 0x7fffu + ((ub >> 16) & 1u);
  return (ua >> 16) | (ub & 0xffff0000u);
}

__device__ __forceinline__ unsigned pkbf(float a, float b) {
#if __has_builtin(__builtin_amdgcn_cvt_pk_bf16_f32)
  auto r = __builtin_amdgcn_cvt_pk_bf16_f32(a, b);
  return __builtin_bit_cast(unsigned, r);
#else
  return f2bf_pack(a, b);
#endif
}

__device__ __forceinline__ void gl_lds16(const void* g, void* l) {
  __builtin_amdgcn_global_load_lds(
      (const __attribute__((address_space(1))) unsigned*)g,
      (__attribute__((address_space(3))) unsigned*)l, 16, 0, 0);
}

// Fragment-major layouts, per 32-s block = 8 slots * 1 KB = 8 KB (4096 ushort):
//  Kf slot kt, lane l=(h*32+s): K[s][d=kt*16+h*8+j], j=0..7   (same as R5-verified)
//  Vf slot (dblk*2+t2), lane l=(h*32+dloc): V^T[d=dblk*32+dloc][s_perm]
//    with s_perm = t2*16 + 4*h + (j&3) + 8*(j>>2)   <-- matches S-MFMA C-reg order,
//    so P fragments come straight from acc registers (no shuffles).

// ---------------- pre-pass ----------------
// grid 5120: [0,4096) Q row-norm; [4096,4608) K-blocks; [4608,5120) V-blocks
extern "C" __global__ __launch_bounds__(256)
void prep_kern(const float* __restrict__ Q, const float* __restrict__ K,
               const float* __restrict__ V,
               unsigned short* __restrict__ Qn, unsigned short* __restrict__ Kf,
               unsigned short* __restrict__ Vf) {
  __shared__ float Tf[32 * 130];          // K rows fp32 (padded stride)
  __shared__ float Ps[32 * 8];            // per-row sumsq partials
  __shared__ float Nr[32];                // per-row 1/norm
  __shared__ unsigned short Tb[32 * 128]; // V rows bf16
  const int t = threadIdx.x;
  const int bid = blockIdx.x;
  if (bid < 4096) {  // Q: one row per wave, row-major bf16 out
    const int lane = t & 63;
    const int r = bid * 4 + (t >> 6);
    float2 f = *(const float2*)(Q + (size_t)r * Dd + lane * 2);
    float ss = f.x * f.x + f.y * f.y;
#pragma unroll
    for (int m = 1; m < 64; m <<= 1) ss += __shfl_xor(ss, m, 64);
    float inv = 1.0f / fmaxf(sqrtf(ss), 1e-12f);
    *(unsigned*)(Qn + (size_t)r * Dd + lane * 2) = pkbf(f.x * inv, f.y * inv);
  } else if (bid < 4608) {  // K: 32-row block -> normalize -> frag-major
    const int kb = bid - 4096;
    const int b = kb & 7, sw = kb >> 3;
    const int sl = t >> 3, d0 = (t & 7) * 16;
    const float* src = K + ((size_t)(b * Ss + sw * 32 + sl)) * Dd + d0;
    float ss = 0.f;
#pragma unroll
    for (int i = 0; i < 4; ++i) {
      float4 v = *(const float4*)(src + i * 4);
      Tf[sl * 130 + d0 + i * 4 + 0] = v.x;
      Tf[sl * 130 + d0 + i * 4 + 1] = v.y;
      Tf[sl * 130 + d0 + i * 4 + 2] = v.z;
      Tf[sl * 130 + d0 + i * 4 + 3] = v.w;
      ss += v.x * v.x + v.y * v.y + v.z * v.z + v.w * v.w;
    }
    Ps[sl * 8 + (t & 7)] = ss;
    __syncthreads();
    if (t < 32) {
      float s = 0.f;
#pragma unroll
      for (int j = 0; j < 8; ++j) s += Ps[t * 8 + j];
      Nr[t] = 1.0f / fmaxf(sqrtf(s), 1e-12f);
    }
    __syncthreads();
    unsigned short* Ko = Kf + ((size_t)(b * 64 + sw)) * 4096;
#pragma unroll
    for (int p = 0; p < 2; ++p) {
      const int run = p * 256 + t;
      const int lane = run & 63, s = lane & 31, h = lane >> 5;
      const int d = (run >> 6) * 16 + h * 8;
      const float n = Nr[s];
      const float* row = &Tf[s * 130 + d];
      uint4 w;
      w.x = pkbf(row[0] * n, row[1] * n);
      w.y = pkbf(row[2] * n, row[3] * n);
      w.z = pkbf(row[4] * n, row[5] * n);
      w.w = pkbf(row[6] * n, row[7] * n);
      *(uint4*)(Ko + run * 8) = w;  // lane-contiguous 16 B
    }
  } else {  // V: 32-row block -> transpose -> j-permuted frag-major
    const int vb = bid - 4608;
    const int b = vb & 7, sw = vb >> 3;
    const int sl = t >> 3, d0 = (t & 7) * 16;
    const float* src = V + ((size_t)(b * Ss + sw * 32 + sl)) * Dd + d0;
#pragma unroll
    for (int i = 0; i < 4; ++i) {
      float4 v = *(const float4*)(src + i * 4);
      *(unsigned*)&Tb[sl * 128 + d0 + i * 4]     = pkbf(v.x, v.y);
      *(unsigned*)&Tb[sl * 128 + d0 + i * 4 + 2] = pkbf(v.z, v.w);
    }
    __syncthreads();
    unsigned short* Vo = Vf + ((size_t)(b * 64 + sw)) * 4096;
#pragma unroll
    for (int p = 0; p < 2; ++p) {
      const int run = p * 256 + t;
      const int vslot = run >> 6, lane = run & 63;
      const int dloc = lane & 31, h = lane >> 5;
      const int dblk = vslot >> 1, t2 = vslot & 1;
      const int d = dblk * 32 + dloc;
      unsigned short w[8];
#pragma unroll
      for (int j = 0; j < 8; ++j) {
        const int sloc = t2 * 16 + 4 * h + (j & 3) + 8 * (j >> 2);
        w[j] = Tb[sloc * 128 + d];
      }
      *(uint4*)(Vo + run * 8) = *(uint4*)w;  // lane-contiguous 16 B
    }
  }
}

// ---------------- main fused attention ----------------
// grid 512: gid = qt*32 + b*4 + sb; 4 waves, 32 q-rows each; SCHUNK=512,
// 64-s tile per iter (2x 32-s blocks), LDS dbuf 64 KB -> 2 WG/CU.
// Fully-coalesced gl_lds16 staging; shuffle-free P via permuted Vf.
extern "C" __global__ __launch_bounds__(256, 2)
void attn_kern(const unsigned short* __restrict__ Qn,
               const unsigned short* __restrict__ Kf,
               const unsigned short* __restrict__ Vf,
               unsigned short* __restrict__ Op,
               float* __restrict__ Lp) {
  __shared__ unsigned short Kl[2][16 * 512];
  __shared__ unsigned short Vl[2][16 * 512];
  const int tid = threadIdx.x, wv = tid >> 6, lane = tid & 63;
  const int lm = lane & 31, h = lane >> 5;
  const int gid = blockIdx.x;
  const int qt = gid >> 5, b = (gid >> 2) & 7, sb = gid & 3;
  const int sblk0 = sb * (SCHUNK / 32);
  const int qrow = qt * 128 + wv * 32 + lm;

  const unsigned short* Qrow = Qn + ((size_t)(b * Ll + qrow)) * Dd;
  bf16x8 qf[8];
#pragma unroll
  for (int kt = 0; kt < 8; ++kt)
    qf[kt] = *(const bf16x8*)(Qrow + kt * 16 + h * 8);

  const unsigned short* Kc = Kf + ((size_t)(b * 64 + sblk0)) * 4096;
  const unsigned short* Vc = Vf + ((size_t)(b * 64 + sblk0)) * 4096;

  f32x16 o[4];
#pragma unroll
  for (int i = 0; i < 4; ++i)
#pragma unroll
    for (int r = 0; r < 16; ++r) o[i][r] = 0.f;

  auto stage = [&](int it, int buf) {
#pragma unroll
    for (int i = 0; i < 4; ++i) {
      const int sl = wv * 4 + i;  // 16 slots: (sblk<<3)|kt
      gl_lds16(Kc + (size_t)(it * 2 + (sl >> 3)) * 4096 + (sl & 7) * 512 + lane * 8,
               &Kl[buf][sl * 512]);
      gl_lds16(Vc + (size_t)(it * 2 + (sl >> 3)) * 4096 + (sl & 7) * 512 + lane * 8,
               &Vl[buf][sl * 512]);
    }
  };
  stage(0, 0);

  float lrun = 0.f;

#pragma unroll 1
  for (int it = 0; it < 8; ++it) {
    __syncthreads();  // drains vmcnt: cur staged; prev buffer reads done
    const int cur = it & 1;
    if (it + 1 < 8) stage(it + 1, cur ^ 1);

#pragma unroll
    for (int sblk = 0; sblk < 2; ++sblk) {
      // S^T = K · Q^T  (M=s 32, N=m 32, K=d 8x16)
      f32x16 acc;
#pragma unroll
      for (int r = 0; r < 16; ++r) acc[r] = 0.f;
#pragma unroll
      for (int kt = 0; kt < 8; ++kt) {
        bf16x8 kf = *(const bf16x8*)&Kl[cur][(sblk * 8 + kt) * 512 + lane * 8];
        acc = __builtin_amdgcn_mfma_f32_32x32x16_bf16(kf, qf[kt], acc, 0, 0, 0);
      }
      // fixed-max softmax; P B-frag = consecutive acc regs (no shuffles)
#pragma unroll
      for (int t2 = 0; t2 < 2; ++t2) {
        float p[8];
#pragma unroll
        for (int j = 0; j < 8; ++j)
          p[j] = __builtin_amdgcn_exp2f(
              __builtin_fmaf(acc[t2 * 8 + j], SCALE_LOG2E, -SCALE_LOG2E));
        lrun += ((p[0] + p[1]) + (p[2] + p[3])) + ((p[4] + p[5]) + (p[6] + p[7]));
        uint4 fr;
        fr.x = pkbf(p[0], p[1]);
        fr.y = pkbf(p[2], p[3]);
        fr.z = pkbf(p[4], p[5]);
        fr.w = pkbf(p[6], p[7]);
        bf16x8 pf = __builtin_bit_cast(bf16x8, fr);
        // O^T += V^T · P^T  (M=d 4x32, N=m 32, K=s 16, s-order permuted to match)
#pragma unroll
        for (int dblk = 0; dblk < 4; ++dblk) {
          bf16x8 vf =
              *(const bf16x8*)&Vl[cur][(sblk * 8 + dblk * 2 + t2) * 512 + lane * 8];
          o[dblk] = __builtin_amdgcn_mfma_f32_32x32x16_bf16(vf, pf, o[dblk], 0, 0, 0);
        }
      }
    }
  }

  // epilogue: partial (unnormalized) O bf16 + per-row l (shared fixed max)
  const float lt = lrun + __shfl_xor(lrun, 32, 64);
  unsigned short* Ob = Op + ((size_t)sb * NROWS + b * Ll + qrow) * Dd;
#pragma unroll
  for (int dblk = 0; dblk < 4; ++dblk)
#pragma unroll
    for (int g = 0; g < 4; ++g) {
      uint2 w;
      w.x = pkbf(o[dblk][g * 4 + 0], o[dblk][g * 4 + 1]);
      w.y = pkbf(o[dblk][g * 4 + 2], o[dblk][g * 4 + 3]);
      *(uint2*)(Ob + dblk * 32 + g * 8 + h * 4) = w;  // d = 32*dblk + 8*g + 4*h
    }
  if (h == 0) Lp[sb * NROWS + b * Ll + qrow] = lt;
}

// ---------------- combine the NSB S-chunk partials (pure sum: shared max) ---
extern "C" __global__ __launch_bounds__(256)
void comb_kern(const unsigned short* __restrict__ Op,
               const float* __restrict__ Lp, float* __restrict__ Out) {
  const int idx = blockIdx.x * 256 + threadIdx.x;  // one thread per 4 d
  const int row = idx >> 5;
  const int dof = (idx & 31) * 4;
  float den = 0.f;
#pragma unroll
  for (int s = 0; s < NSB; ++s) den += Lp[s * NROWS + row];
  float a0 = 0.f, a1 = 0.f, a2 = 0.f, a3 = 0.f;
#pragma unroll
  for (int s = 0; s < NSB; ++s) {
    uint2 v = *(const uint2*)(Op + ((size_t)s * NROWS + row) * Dd + dof);
    a0 += __uint_as_float(v.x << 16);
    a1 += __uint_as_float(v.x & 0xffff0000u);
    a2 += __uint_as_float(v.y << 16);
    a3 += __uint_as_float(v.y & 0xffff0000u);
  }
  const float inv = 1.f / den;
  float4 r; r.x = a0 * inv; r.y = a1 * inv; r.z = a2 * inv; r.w = a3 * inv;
  *(float4*)(Out + (size_t)row * Dd + dof) = r;
}

extern "C" void kernel_launch(void* const* d_in, const int* in_sizes, int n_in,
                              void* d_out, int out_size, void* d_ws, size_t ws_size,
                              hipStream_t stream) {
  const float* Q = (const float*)d_in[0];
  const float* K = (const float*)d_in[1];
  const float* V = (const float*)d_in[2];
  float* Out = (float*)d_out;
  unsigned short* Qn = (unsigned short*)d_ws;                  // 4 MiB
  unsigned short* Kf = Qn + (size_t)NROWS * Dd;                // 4 MiB (frag-major)
  unsigned short* Vf = Kf + (size_t)NROWS * Dd;                // 4 MiB (frag-major, j-permuted)
  unsigned short* Op = Vf + (size_t)Bb * Dd * Ss;              // 16 MiB (bf16 partials)
  float* Lp = (float*)(Op + (size_t)NSB * NROWS * Dd);         // 256 KiB
  hipLaunchKernelGGL(prep_kern, dim3(4096 + 512 + 512), dim3(256), 0, stream,
                     Q, K, V, Qn, Kf, Vf);
  hipLaunchKernelGGL(attn_kern, dim3(512), dim3(256), 0, stream, Qn, Kf, Vf, Op, Lp);
  hipLaunchKernelGGL(comb_kern, dim3(2048), dim3(256), 0, stream, Op, Lp, Out);
}